// Round 5
// baseline (908.036 us; speedup 1.0000x reference)
//
#include <hip/hip_runtime.h>

#define BINS 10
#define TPB  256
#define NBLK 4096

// ws layout (21 dwords): unsigned ticket; float bsum[BINS]; int bcnt[BINS]
// (harness poisons ws to 0xAA before every launch -> zero-kernel inits it)

__global__ __launch_bounds__(64) void ghmc_zero(unsigned* ws) {
    int i = threadIdx.x;
    if (i < 1 + 2 * BINS) ws[i] = 0u;
}

// Per-element update, all in registers (round-3: per-element LDS atomics are a
// ~137us floor; round-2: 10-way select chain ~2x the math cost).
// Algebra: t in {0,1} -> y = p*(1-2t); g = sigmoid(y); bce = softplus(y).
// Binning in y-space: g >= b/10 <=> y >= logit(b/10); sigmoid never computed.
// Cumulative sums S_b / counts; per-bin recovered as S_b - S_{b+1} per lane.
// Invalid (w==0): ye=-60 -> below all thresholds, softplus(-60)==0.0f exactly.
#define GHMC_ELEM(pk, tk, wk)                                                 \
    do {                                                                      \
        float tm_ = __builtin_fmaf((tk), -2.0f, 1.0f);  /* {1,-1} exact */    \
        float y_  = tm_ * (pk);                                               \
        bool  v_  = ((wk) > 0.0f);                                            \
        float ye_ = v_ ? y_ : -60.0f;                                         \
        float e_  = __expf(-__builtin_fabsf(ye_));      /* (0,1] */           \
        float onep_ = 1.0f + e_;                        /* (1,2]: log exact */\
        float bce_  = __builtin_fmaf(0.69314718055994530942f,                 \
                                     __log2f(onep_),                          \
                                     __builtin_fmaxf(ye_, 0.0f));             \
        S[0] += bce_;                                                         \
        C0   += v_ ? 1 : 0;                                                   \
        _Pragma("unroll")                                                     \
        for (int b_ = 1; b_ <= 5; ++b_) {                                     \
            bool ge_ = (ye_ >= kL[b_ - 1]);                                   \
            S[b_] += ge_ ? bce_ : 0.0f;                                       \
            cLo   += ge_ ? (1u << (6 * (b_ - 1))) : 0u;                       \
        }                                                                     \
        _Pragma("unroll")                                                     \
        for (int b_ = 6; b_ <= 9; ++b_) {                                     \
            bool ge_ = (ye_ >= kL[b_ - 1]);                                   \
            S[b_] += ge_ ? bce_ : 0.0f;                                       \
            cHi   += ge_ ? (1u << (6 * (b_ - 6))) : 0u;                       \
        }                                                                     \
    } while (0)

#define GHMC_ELEM4(P, T, W)                                                   \
    do {                                                                      \
        GHMC_ELEM((P).x, (T).x, (W).x);                                       \
        GHMC_ELEM((P).y, (T).y, (W).y);                                       \
        GHMC_ELEM((P).z, (T).z, (W).z);                                       \
        GHMC_ELEM((P).w, (T).w, (W).w);                                       \
    } while (0)

__global__ __launch_bounds__(256, 8) void ghmc_main(
    const float* __restrict__ pred, const float* __restrict__ targ,
    const float* __restrict__ lw,
    unsigned* __restrict__ ticket, float* __restrict__ bsum,
    int* __restrict__ bcnt, float* __restrict__ out, int n) {

    // logit(b/10), b=1..9
    const float kL[9] = { -2.1972246f, -1.3862944f, -0.84729786f, -0.40546511f,
                          0.0f, 0.40546511f, 0.84729786f, 1.3862944f, 2.1972246f };

    float S[BINS];
#pragma unroll
    for (int b = 0; b < BINS; ++b) S[b] = 0.0f;
    int C0 = 0;
    unsigned cLo = 0u, cHi = 0u;   // bins 1-5 / 6-9, 6 bits each (<=41/lane)

    const int nvec = n >> 2;
    // contiguous chunk per block (4096 blocks -> 5 vec4/thread, fine tail grain)
    const int start = (int)(((long long)nvec * blockIdx.x) / gridDim.x);
    const int end   = (int)(((long long)nvec * (blockIdx.x + 1)) / gridDim.x);

    const float4* p4 = (const float4*)pred;
    const float4* t4 = (const float4*)targ;
    const float4* w4 = (const float4*)lw;

    // ---- depth-2 software pipeline: 2 load batches (6 loads) in flight ----
    const int i0 = start + (int)threadIdx.x;
    float4 p0, t0, w0, p1, t1, w1;
    const bool h0 = (i0 < end);
    if (h0) { p0 = p4[i0]; t0 = t4[i0]; w0 = w4[i0]; }
    const int i1 = i0 + TPB;
    const bool h1 = (i1 < end);
    if (h1) { p1 = p4[i1]; t1 = t4[i1]; w1 = w4[i1]; }

    for (int j = i0 + 2 * TPB; j < end; j += TPB) {
        float4 pn = p4[j], tn = t4[j], wn = w4[j];
        GHMC_ELEM4(p0, t0, w0);
        p0 = p1; t0 = t1; w0 = w1;
        p1 = pn; t1 = tn; w1 = wn;
    }
    if (h0) GHMC_ELEM4(p0, t0, w0);
    if (h1) GHMC_ELEM4(p1, t1, w1);

    // scalar tail (n not divisible by 4)
    {
        int rem  = n & 3;
        int gtid = blockIdx.x * TPB + (int)threadIdx.x;
        if (gtid < rem) {
            int idx = (nvec << 2) + gtid;
            float pk = pred[idx], tk = targ[idx], wk = lw[idx];
            GHMC_ELEM(pk, tk, wk);
        }
    }

    // per-lane: cumulative -> per-bin
    float lsum[BINS];
    int   lcnt[BINS];
    {
        int Cc[BINS];
        Cc[0] = C0;
#pragma unroll
        for (int b = 1; b <= 5; ++b) Cc[b] = (int)((cLo >> (6 * (b - 1))) & 63u);
#pragma unroll
        for (int b = 6; b <= 9; ++b) Cc[b] = (int)((cHi >> (6 * (b - 6))) & 63u);
#pragma unroll
        for (int b = 0; b < BINS - 1; ++b) {
            lsum[b] = S[b] - S[b + 1];
            lcnt[b] = Cc[b] - Cc[b + 1];
        }
        lsum[BINS - 1] = S[BINS - 1];
        lcnt[BINS - 1] = Cc[BINS - 1];
    }

    // ---- wave butterfly, then block LDS, then one global atomic per bin ----
    __shared__ float s_bsum[BINS];
    __shared__ int   s_bcnt[BINS];
    __shared__ int   s_last;
    if (threadIdx.x < BINS) { s_bsum[threadIdx.x] = 0.0f; s_bcnt[threadIdx.x] = 0; }
    __syncthreads();

    const int lane = threadIdx.x & 63;
#pragma unroll
    for (int b = 0; b < BINS; ++b) {
        float s = lsum[b];
        int   c = lcnt[b];
#pragma unroll
        for (int off = 32; off > 0; off >>= 1) {
            s += __shfl_xor(s, off, 64);
            c += __shfl_xor(c, off, 64);
        }
        if (lane == 0 && c != 0) {
            atomicAdd(&s_bsum[b], s);
            atomicAdd(&s_bcnt[b], c);
        }
    }
    __syncthreads();

    if (threadIdx.x < BINS) {
        float s = s_bsum[threadIdx.x];
        int   c = s_bcnt[threadIdx.x];
        if (c != 0) {
            atomicAdd(&bsum[threadIdx.x], s);   // device-scope by default
            atomicAdd(&bcnt[threadIdx.x], c);
        }
    }
    __threadfence();      // release: this thread's global atomics visible
    __syncthreads();      // whole block done + fenced

    // ---- last-block-done: fold the finalize kernel into main ----
    if (threadIdx.x == 0) {
        unsigned old = atomicAdd(ticket, 1u);
        s_last = (old == (unsigned)(gridDim.x - 1)) ? 1 : 0;
    }
    __syncthreads();

    if (s_last && threadIdx.x == 0) {
        __threadfence();  // acquire: all other blocks' atomics visible
        float acc = 0.0f;
        int nb = 0;
#pragma unroll
        for (int b = 0; b < BINS; ++b) {
            int c = atomicAdd(&bcnt[b], 0);           // device-coherent read
            if (c > 0) {
                float s = atomicAdd(&bsum[b], 0.0f);  // device-coherent read
                nb += 1;
                acc += s / (float)c;
            }
        }
        out[0] = (nb > 0) ? (acc / (float)nb) : 0.0f;  // LOSS_WEIGHT = 1
    }
}

extern "C" void kernel_launch(void* const* d_in, const int* in_sizes, int n_in,
                              void* d_out, int out_size, void* d_ws, size_t ws_size,
                              hipStream_t stream) {
    const float* pred = (const float*)d_in[0];
    const float* targ = (const float*)d_in[1];
    const float* lw   = (const float*)d_in[2];
    float* out = (float*)d_out;
    const int n = in_sizes[0];   // 262144*80 = 20,971,520

    unsigned* ticket = (unsigned*)d_ws;
    float*    bsum   = (float*)((char*)d_ws + 4);
    int*      bcnt   = (int*)((char*)d_ws + 4 + BINS * sizeof(float));

    ghmc_zero<<<1, 64, 0, stream>>>((unsigned*)d_ws);

    ghmc_main<<<NBLK, TPB, 0, stream>>>(pred, targ, lw,
                                        ticket, bsum, bcnt, out, n);
}

// Round 6
// 524.233 us; speedup vs baseline: 1.7321x; 1.7321x over previous
//
#include <hip/hip_runtime.h>

#define BINS 10
#define TPB  256
#define NBLK 2048

// ws layout (21 dwords): unsigned ticket; float bsum[BINS]; int bcnt[BINS]
// (harness poisons ws to 0xAA before every launch -> zero-kernel inits it)

__global__ __launch_bounds__(64) void ghmc_zero(unsigned* ws) {
    int i = threadIdx.x;
    if (i < 1 + 2 * BINS) ws[i] = 0u;
}

// Per-element update.
//  - sums: per-lane VGPR cumulative-threshold form (round-4), v_cmp+cndmask+add
//  - counts: per-WAVE in SGPRs via popcount(ballot(pred)) -- s_bcnt1_b64+s_add
//    on the scalar pipe, co-issues with VALU; removes ~18 VALU/elem and frees
//    the packed-count VGPR state (round-5 spilled: WRITE_SIZE 116 MB of scratch)
// Algebra: t in {0,1} -> y = p*(1-2t); bce = softplus(y); bin via y >= logit(b/10).
// Invalid (w==0): ye=-60 -> below all thresholds, softplus(-60)==0.0f exactly.
// NOTE count uniformity: W[] is wave-uniform only if whole-wave control flow is
// uniform; in the tail, active lanes are 0..rem-1 (contiguous from lane 0), so
// lane 0 always holds the complete count.
#define GHMC_ELEM(pk, tk, wk)                                                 \
    do {                                                                      \
        float tm_ = __builtin_fmaf((tk), -2.0f, 1.0f);  /* {1,-1} exact */    \
        float y_  = tm_ * (pk);                                               \
        bool  v_  = ((wk) > 0.0f);                                            \
        float ye_ = v_ ? y_ : -60.0f;                                         \
        float e_  = __expf(-__builtin_fabsf(ye_));      /* (0,1] */           \
        float onep_ = 1.0f + e_;                        /* (1,2]: log exact */\
        float bce_  = __builtin_fmaf(0.69314718055994530942f,                 \
                                     __log2f(onep_),                          \
                                     __builtin_fmaxf(ye_, 0.0f));             \
        S[0] += bce_;                                                         \
        W[0] += (int)__popcll(__ballot(v_));                                  \
        _Pragma("unroll")                                                     \
        for (int b_ = 1; b_ < BINS; ++b_) {                                   \
            bool ge_ = (ye_ >= kL[b_ - 1]);                                   \
            S[b_] += ge_ ? bce_ : 0.0f;                                       \
            W[b_] += (int)__popcll(__ballot(ge_));                            \
        }                                                                     \
    } while (0)

#define GHMC_ELEM4(P, T, W_)                                                  \
    do {                                                                      \
        GHMC_ELEM((P).x, (T).x, (W_).x);                                      \
        GHMC_ELEM((P).y, (T).y, (W_).y);                                      \
        GHMC_ELEM((P).z, (T).z, (W_).z);                                      \
        GHMC_ELEM((P).w, (T).w, (W_).w);                                      \
    } while (0)

__global__ __launch_bounds__(256) void ghmc_main(
    const float* __restrict__ pred, const float* __restrict__ targ,
    const float* __restrict__ lw,
    unsigned* __restrict__ ticket, float* __restrict__ bsum,
    int* __restrict__ bcnt, float* __restrict__ out, int n) {

    // logit(b/10), b=1..9
    const float kL[9] = { -2.1972246f, -1.3862944f, -0.84729786f, -0.40546511f,
                          0.0f, 0.40546511f, 0.84729786f, 1.3862944f, 2.1972246f };

    float S[BINS];     // per-lane cumulative sums (VGPR)
    int   W[BINS];     // per-wave cumulative counts (SGPR: ballot+popcount)
#pragma unroll
    for (int b = 0; b < BINS; ++b) { S[b] = 0.0f; W[b] = 0; }

    const int nvec = n >> 2;
    // contiguous chunk per block (2048 blocks -> exactly 10 vec4/thread here)
    const int start = (int)(((long long)nvec * blockIdx.x) / gridDim.x);
    const int end   = (int)(((long long)nvec * (blockIdx.x + 1)) / gridDim.x);

    const float4* p4 = (const float4*)pred;
    const float4* t4 = (const float4*)targ;
    const float4* w4 = (const float4*)lw;

    // ---- depth-2 software pipeline: 6 vec4 loads (6 KB/wave) in flight ----
    const int i0 = start + (int)threadIdx.x;
    const int i1 = i0 + TPB;
    float4 p0, t0, w0, p1, t1, w1;
    const bool h0 = (i0 < end);
    const bool h1 = (i1 < end);
    if (h0) { p0 = p4[i0]; t0 = t4[i0]; w0 = w4[i0]; }
    if (h1) { p1 = p4[i1]; t1 = t4[i1]; w1 = w4[i1]; }

    for (int j = i0 + 2 * TPB; j < end; j += TPB) {
        float4 pn = p4[j], tn = t4[j], wn = w4[j];
        GHMC_ELEM4(p0, t0, w0);
        p0 = p1; t0 = t1; w0 = w1;
        p1 = pn; t1 = tn; w1 = wn;
    }
    if (h0) GHMC_ELEM4(p0, t0, w0);
    if (h1) GHMC_ELEM4(p1, t1, w1);

    // scalar tail (n not divisible by 4; rem<=3 -> lanes 0..2 of block 0)
    {
        int rem  = n & 3;
        int gtid = blockIdx.x * TPB + (int)threadIdx.x;
        if (gtid < rem) {
            int idx = (nvec << 2) + gtid;
            float pk = pred[idx], tk = targ[idx], wk = lw[idx];
            GHMC_ELEM(pk, tk, wk);
        }
    }

    // per-lane cumulative -> per-bin sums; per-wave cumulative -> per-bin counts
    float lsum[BINS];
    int   wcnt[BINS];
#pragma unroll
    for (int b = 0; b < BINS - 1; ++b) {
        lsum[b] = S[b] - S[b + 1];
        wcnt[b] = W[b] - W[b + 1];
    }
    lsum[BINS - 1] = S[BINS - 1];
    wcnt[BINS - 1] = W[BINS - 1];

    // ---- wave butterfly (sums only), block LDS, one global atomic per bin ----
    __shared__ float s_bsum[BINS];
    __shared__ int   s_bcnt[BINS];
    __shared__ int   s_last;
    if (threadIdx.x < BINS) { s_bsum[threadIdx.x] = 0.0f; s_bcnt[threadIdx.x] = 0; }
    __syncthreads();

    const int lane = threadIdx.x & 63;
#pragma unroll
    for (int b = 0; b < BINS; ++b) {
        float s = lsum[b];
#pragma unroll
        for (int off = 32; off > 0; off >>= 1)
            s += __shfl_xor(s, off, 64);
        if (lane == 0 && wcnt[b] != 0) {
            atomicAdd(&s_bsum[b], s);
            atomicAdd(&s_bcnt[b], wcnt[b]);
        }
    }
    __syncthreads();

    if (threadIdx.x < BINS) {
        float s = s_bsum[threadIdx.x];
        int   c = s_bcnt[threadIdx.x];
        if (c != 0) {
            atomicAdd(&bsum[threadIdx.x], s);   // device-scope by default
            atomicAdd(&bcnt[threadIdx.x], c);
        }
    }
    __threadfence();      // release: this block's global atomics visible
    __syncthreads();      // whole block done + fenced

    // ---- last-block-done: finalize fused into main (saves one ~15us launch) --
    if (threadIdx.x == 0) {
        unsigned old = atomicAdd(ticket, 1u);
        s_last = (old == (unsigned)(gridDim.x - 1)) ? 1 : 0;
    }
    __syncthreads();

    if (s_last && threadIdx.x == 0) {
        __threadfence();  // acquire: all other blocks' atomics visible
        float acc = 0.0f;
        int nb = 0;
#pragma unroll
        for (int b = 0; b < BINS; ++b) {
            int c = atomicAdd(&bcnt[b], 0);           // device-coherent read
            if (c > 0) {
                float s = atomicAdd(&bsum[b], 0.0f);  // device-coherent read
                nb += 1;
                acc += s / (float)c;
            }
        }
        out[0] = (nb > 0) ? (acc / (float)nb) : 0.0f;  // LOSS_WEIGHT = 1
    }
}

extern "C" void kernel_launch(void* const* d_in, const int* in_sizes, int n_in,
                              void* d_out, int out_size, void* d_ws, size_t ws_size,
                              hipStream_t stream) {
    const float* pred = (const float*)d_in[0];
    const float* targ = (const float*)d_in[1];
    const float* lw   = (const float*)d_in[2];
    float* out = (float*)d_out;
    const int n = in_sizes[0];   // 262144*80 = 20,971,520

    unsigned* ticket = (unsigned*)d_ws;
    float*    bsum   = (float*)((char*)d_ws + 4);
    int*      bcnt   = (int*)((char*)d_ws + 4 + BINS * sizeof(float));

    ghmc_zero<<<1, 64, 0, stream>>>((unsigned*)d_ws);

    ghmc_main<<<NBLK, TPB, 0, stream>>>(pred, targ, lw,
                                        ticket, bsum, bcnt, out, n);
}